// Round 1
// baseline (939.090 us; speedup 1.0000x reference)
//
#include <hip/hip_runtime.h>
#include <hip/hip_bf16.h>

typedef __bf16 bf16;
typedef __bf16 bf16x8 __attribute__((ext_vector_type(8)));
typedef float f32x4 __attribute__((ext_vector_type(4)));

#define NB   32768
#define EMB  768
#define MSUB 32
#define KC   256
#define DSUB 24

__device__ __forceinline__ bf16x8 cvt8(float4 a, float4 b) {
    bf16x8 r;
    r[0] = (bf16)a.x; r[1] = (bf16)a.y; r[2] = (bf16)a.z; r[3] = (bf16)a.w;
    r[4] = (bf16)b.x; r[5] = (bf16)b.y; r[6] = (bf16)b.z; r[7] = (bf16)b.w;
    return r;
}

__global__ __launch_bounds__(256, 2)
void pq_fused(const float* __restrict__ x, const float* __restrict__ cb,
              const float* __restrict__ rot, float* __restrict__ out) {
    // xr in bf16, granule layout: [e/8 (97)][row (32)][slot (8)]  = 48.5 KiB
    __shared__ bf16 xr_lds[97 * 32 * 8];

    const int tid  = threadIdx.x;
    const int w    = tid >> 6;        // wave 0..3
    const int lane = tid & 63;
    const int l15  = lane & 15;
    const int lg   = lane >> 4;       // quarter-wave group 0..3
    const int rowbase = blockIdx.x * 32;

    // ---------------- Phase 1: xr = x @ rot^T (bf16 MFMA, fp32 acc) -------
    // wave w computes j in [w*192, w*192+192): 12 j-tiles x 2 row-tiles
    f32x4 acc[2][12];
    #pragma unroll
    for (int rt = 0; rt < 2; ++rt)
        #pragma unroll
        for (int jt = 0; jt < 12; ++jt)
            acc[rt][jt] = (f32x4){0.f, 0.f, 0.f, 0.f};

    const int jbase = w * 192;
    #pragma unroll 2
    for (int e0 = 0; e0 < EMB; e0 += 32) {
        bf16x8 afrag[2];
        #pragma unroll
        for (int rt = 0; rt < 2; ++rt) {
            const float* ap = x + (size_t)(rowbase + rt * 16 + l15) * EMB + e0 + lg * 8;
            float4 a0 = *(const float4*)(ap);
            float4 a1 = *(const float4*)(ap + 4);
            afrag[rt] = cvt8(a0, a1);
        }
        #pragma unroll
        for (int jt = 0; jt < 12; ++jt) {
            const float* bp = rot + (size_t)(jbase + jt * 16 + l15) * EMB + e0 + lg * 8;
            float4 b0 = *(const float4*)(bp);
            float4 b1 = *(const float4*)(bp + 4);
            bf16x8 bfrag = cvt8(b0, b1);
            acc[0][jt] = __builtin_amdgcn_mfma_f32_16x16x32_bf16(afrag[0], bfrag, acc[0][jt], 0, 0, 0);
            acc[1][jt] = __builtin_amdgcn_mfma_f32_16x16x32_bf16(afrag[1], bfrag, acc[1][jt], 0, 0, 0);
        }
    }

    // write xr to LDS in granule layout (C-frag: col j = l15, rows = lg*4+r)
    #pragma unroll
    for (int rt = 0; rt < 2; ++rt) {
        #pragma unroll
        for (int jt = 0; jt < 12; ++jt) {
            const int j    = jbase + jt * 16 + l15;
            const int gE   = j >> 3;
            const int slot = j & 7;
            #pragma unroll
            for (int r = 0; r < 4; ++r) {
                const int row = rt * 16 + lg * 4 + r;
                xr_lds[(gE * 32 + row) * 8 + slot] = (bf16)acc[rt][jt][r];
            }
        }
    }
    // zero granule 96 (read by lg==3 lanes when m==31; avoid NaN poison)
    xr_lds[96 * 32 * 8 + tid] = (bf16)0.f;
    __syncthreads();

    // ---------------- Phase 2: scores = xs . cb (bf16 MFMA) ---------------
    // wave w owns k-tiles [w*4, w*4+4) -> 64 contiguous centroids
    const int ktbase = w * 4;
    const float4 fz = {0.f, 0.f, 0.f, 0.f};
    const bf16x8 bzero = cvt8(fz, fz);

    for (int m = 0; m < MSUB; ++m) {
        // A-frags: lane needs xr[row][m*24 + lg*8 + r]; granule = 3m + lg.
        // lg==3 reads the next granule (garbage but finite / zeroed for m=31);
        // it is multiplied by bfrag==0 there, contributing exactly 0.
        bf16x8 a2[2];
        #pragma unroll
        for (int rt = 0; rt < 2; ++rt)
            a2[rt] = *(const bf16x8*)&xr_lds[((3 * m + lg) * 32 + rt * 16 + l15) * 8];

        #pragma unroll
        for (int kt = 0; kt < 4; ++kt) {
            const int k0 = (ktbase + kt) * 16;
            bf16x8 bfrag;
            if (lg < 3) {
                const float* cp = cb + (size_t)(m * KC + k0 + l15) * DSUB + lg * 8;
                float4 c0 = *(const float4*)(cp);
                float4 c1 = *(const float4*)(cp + 4);
                bfrag = cvt8(c0, c1);
            } else {
                bfrag = bzero;   // d = 24..31 zero padding
            }
            #pragma unroll
            for (int rt = 0; rt < 2; ++rt) {
                f32x4 c = (f32x4){0.f, 0.f, 0.f, 0.f};
                c = __builtin_amdgcn_mfma_f32_16x16x32_bf16(a2[rt], bfrag, c, 0, 0, 0);
                #pragma unroll
                for (int r = 0; r < 4; ++r) {
                    const int brow = rowbase + rt * 16 + lg * 4 + r;
                    out[((size_t)brow * MSUB + m) * KC + k0 + l15] = c[r];
                }
            }
        }
    }
}

extern "C" void kernel_launch(void* const* d_in, const int* in_sizes, int n_in,
                              void* d_out, int out_size, void* d_ws, size_t ws_size,
                              hipStream_t stream) {
    const float* x   = (const float*)d_in[0];   // [32768, 768]
    const float* cbk = (const float*)d_in[1];   // [32, 256, 24]
    const float* rot = (const float*)d_in[2];   // [768, 768]
    float* out = (float*)d_out;                 // [32768, 32, 256]

    dim3 grid(NB / 32);
    dim3 block(256);
    hipLaunchKernelGGL(pq_fused, grid, block, 0, stream, x, cbk, rot, out);
}

// Round 2
// 527.051 us; speedup vs baseline: 1.7818x; 1.7818x over previous
//
#include <hip/hip_runtime.h>
#include <hip/hip_bf16.h>

typedef __bf16 bf16;
typedef __bf16 bf16x8 __attribute__((ext_vector_type(8)));
typedef float f32x4 __attribute__((ext_vector_type(4)));

#define NB   32768
#define EMB  768
#define MSUB 32
#define KC   256
#define DSUB 24

__device__ __forceinline__ bf16x8 cvt8(float4 a, float4 b) {
    bf16x8 r;
    r[0] = (bf16)a.x; r[1] = (bf16)a.y; r[2] = (bf16)a.z; r[3] = (bf16)a.w;
    r[4] = (bf16)b.x; r[5] = (bf16)b.y; r[6] = (bf16)b.z; r[7] = (bf16)b.w;
    return r;
}

__global__ __launch_bounds__(512, 4)
void pq_fused2(const float* __restrict__ x, const float* __restrict__ cb,
               const float* __restrict__ rot, float* __restrict__ out) {
    // xr bf16, granule layout [e/8 (96)][row (32)][slot (8)] = 48 KiB
    __shared__ bf16 xr_lds[96 * 32 * 8];
    // output staging: one m-slice [row (32)][k (256)] fp32, XOR-swizzled = 32 KiB
    __shared__ float stg[32 * 256];

    const int tid  = threadIdx.x;
    const int w    = tid >> 6;        // wave 0..7
    const int lane = tid & 63;
    const int l15  = lane & 15;
    const int lg   = lane >> 4;       // quarter-wave 0..3
    const int rowbase = blockIdx.x * 32;

    // ---------------- Phase 1: xr = x @ rot^T (bf16 MFMA, fp32 acc) -------
    // wave w computes j in [w*96, w*96+96): 6 j-tiles x 2 row-tiles
    f32x4 acc[2][6];
    #pragma unroll
    for (int rt = 0; rt < 2; ++rt)
        #pragma unroll
        for (int jt = 0; jt < 6; ++jt)
            acc[rt][jt] = (f32x4){0.f, 0.f, 0.f, 0.f};

    const int jbase = w * 96;
    #pragma unroll 2
    for (int e0 = 0; e0 < EMB; e0 += 32) {
        bf16x8 afrag[2];
        #pragma unroll
        for (int rt = 0; rt < 2; ++rt) {
            const float* ap = x + (size_t)(rowbase + rt * 16 + l15) * EMB + e0 + lg * 8;
            float4 a0 = *(const float4*)(ap);
            float4 a1 = *(const float4*)(ap + 4);
            afrag[rt] = cvt8(a0, a1);
        }
        #pragma unroll
        for (int jt = 0; jt < 6; ++jt) {
            const float* bp = rot + (size_t)(jbase + jt * 16 + l15) * EMB + e0 + lg * 8;
            float4 b0 = *(const float4*)(bp);
            float4 b1 = *(const float4*)(bp + 4);
            bf16x8 bfrag = cvt8(b0, b1);
            acc[0][jt] = __builtin_amdgcn_mfma_f32_16x16x32_bf16(afrag[0], bfrag, acc[0][jt], 0, 0, 0);
            acc[1][jt] = __builtin_amdgcn_mfma_f32_16x16x32_bf16(afrag[1], bfrag, acc[1][jt], 0, 0, 0);
        }
    }

    // write xr to LDS in granule layout (C-frag: col j = l15, rows = lg*4+r)
    #pragma unroll
    for (int rt = 0; rt < 2; ++rt) {
        #pragma unroll
        for (int jt = 0; jt < 6; ++jt) {
            const int j    = jbase + jt * 16 + l15;
            const int gE   = j >> 3;
            const int slot = j & 7;
            #pragma unroll
            for (int r = 0; r < 4; ++r) {
                const int row = rt * 16 + lg * 4 + r;
                xr_lds[(gE * 32 + row) * 8 + slot] = (bf16)acc[rt][jt][r];
            }
        }
    }
    __syncthreads();

    // ---------------- Phase 2: scores = xs . cb (bf16 MFMA) ---------------
    // wave w owns k in [w*32, w*32+32): 2 k-tiles of 16
    const int kw = w * 32;
    const float4 fz = {0.f, 0.f, 0.f, 0.f};
    const bf16x8 bzero = cvt8(fz, fz);

    // cb fragment loader (double-buffered by caller, static indexing only)
    auto load_cb = [&](int m, bf16x8* dst) {
        #pragma unroll
        for (int kt2 = 0; kt2 < 2; ++kt2) {
            if (lg < 3) {
                const float* cp = cb + (size_t)(m * KC + kw + kt2 * 16 + l15) * DSUB + lg * 8;
                float4 c0 = *(const float4*)(cp);
                float4 c1 = *(const float4*)(cp + 4);
                dst[kt2] = cvt8(c0, c1);
            } else {
                dst[kt2] = bzero;  // d = 24..31 zero padding
            }
        }
    };

    auto body = [&](int m, const bf16x8* cbf) {
        // A-frags: granule 3m+lg; lg==3 would be granule 3m+3 (valid except
        // m==31 -> 96); clamp to 95 (finite garbage x B==0 contributes 0).
        int g = 3 * m + lg;
        if (g > 95) g = 95;
        bf16x8 a2[2];
        #pragma unroll
        for (int rt = 0; rt < 2; ++rt)
            a2[rt] = *(const bf16x8*)&xr_lds[(g * 32 + rt * 16 + l15) * 8];

        f32x4 c[2][2];
        #pragma unroll
        for (int kt2 = 0; kt2 < 2; ++kt2)
            #pragma unroll
            for (int rt = 0; rt < 2; ++rt)
                c[kt2][rt] = __builtin_amdgcn_mfma_f32_16x16x32_bf16(
                    a2[rt], cbf[kt2], (f32x4){0.f, 0.f, 0.f, 0.f}, 0, 0, 0);

        __syncthreads();   // previous m's staging reads complete
        #pragma unroll
        for (int kt2 = 0; kt2 < 2; ++kt2) {
            #pragma unroll
            for (int rt = 0; rt < 2; ++rt) {
                const int swz = (lg & 1) << 4;   // ((row>>2)&1)<<4, row=rt*16+lg*4+r
                const int k   = kw + kt2 * 16 + l15;
                #pragma unroll
                for (int r = 0; r < 4; ++r) {
                    const int row = rt * 16 + lg * 4 + r;
                    stg[row * 256 + (k ^ swz)] = c[kt2][rt][r];
                }
            }
        }
        __syncthreads();   // staging complete
        // readback + 1 KiB contiguous nontemporal store per wave-instr
        #pragma unroll
        for (int j = 0; j < 4; ++j) {
            const int row = j * 8 + w;
            const int swz = ((row >> 2) & 1) << 4;
            f32x4 v = *(const f32x4*)&stg[row * 256 + ((4 * lane) ^ swz)];
            float* op = out + ((size_t)(rowbase + row) * MSUB + m) * KC + 4 * lane;
            __builtin_nontemporal_store(v, (f32x4*)op);
        }
    };

    bf16x8 cbA[2], cbB[2];
    load_cb(0, cbA);
    #pragma unroll 1
    for (int m = 0; m < MSUB; m += 2) {
        load_cb(m + 1, cbB);          // prefetch odd
        body(m, cbA);
        if (m + 2 < MSUB) load_cb(m + 2, cbA);  // prefetch next even
        body(m + 1, cbB);
    }
}

extern "C" void kernel_launch(void* const* d_in, const int* in_sizes, int n_in,
                              void* d_out, int out_size, void* d_ws, size_t ws_size,
                              hipStream_t stream) {
    const float* x   = (const float*)d_in[0];   // [32768, 768]
    const float* cbk = (const float*)d_in[1];   // [32, 256, 24]
    const float* rot = (const float*)d_in[2];   // [768, 768]
    float* out = (float*)d_out;                 // [32768, 32, 256]

    dim3 grid(NB / 32);
    dim3 block(512);
    hipLaunchKernelGGL(pq_fused2, grid, block, 0, stream, x, cbk, rot, out);
}